// Round 2
// baseline (559.396 us; speedup 1.0000x reference)
//
#include <hip/hip_runtime.h>
#include <cstddef>

// ---------------------------------------------------------------------------
// CLSTMCell fused as one bf16 GEMM + epilogue.
//   X (4096 x 4096)  = [xr | xi | hr | hi] rows  (bf16, packed in ws)
//   W (8192 x 4096)  rows n = o*8 + g*2 + p, k-quarters [UwR,-UwI,WwR,-WwI] (p=0)
//                                            [UwI, UwR, WwI, WwR]           (p=1)
//   z = X @ W^T + bias ; epilogue: gates -> c_t, h_t  (fp32 out)
//
// R4: 256^2 8-wave counted-vmcnt schedule (m201 template): BM=BN=256 BK=64,
//   8 waves (2Mx4N), 128KiB double-buffered LDS. Per K-tile: issue next
//   tile's 8 global_load_lds -> s_waitcnt vmcnt(8) (never drain to 0 in the
//   loop) -> 4 phases of {4x ds_read_b128 A-frags, barrier, 16 MFMA under
//   setprio(1), barrier}. B-frags (8 ds_reads) once per tile.
//
// R5 post-mortem (CRITICAL, do not regress): __launch_bounds__(512, 2) made
//   the compiler target a 128-VGPR tier -> acc[8][4] (128 f32) SPILLED to
//   scratch: VGPR_Count 124, WRITE_SIZE +234MB (= one acc spill/refill per
//   thread), MfmaUtil 30%, GEMM 392us. Occupancy is LDS-bound at 1 block/CU
//   (128KiB of 160KiB) regardless of VGPRs -> there is NOTHING to gain from
//   a register cap. Use plain __launch_bounds__(512). Same lesson as R2/R3
//   on the old 128^2 kernel. Verify: no scratch (WRITE_SIZE ~133MB).
// ---------------------------------------------------------------------------

typedef short bf16x8 __attribute__((ext_vector_type(8)));   // 8 bf16 (4 VGPRs)
typedef float f32x4  __attribute__((ext_vector_type(4)));
typedef unsigned int u32x4 __attribute__((ext_vector_type(4)));

static constexpr int KDIM = 4096;
static constexpr size_t HOFF = (size_t)4096 * 2048;   // out offset of c_t

__device__ __forceinline__ unsigned short f2bf(float f) {
    unsigned u = __float_as_uint(f);
    u += 0x7FFF + ((u >> 16) & 1);      // RNE
    return (unsigned short)(u >> 16);
}

__device__ __forceinline__ u32x4 pack8(float4 a, float4 b) {
    u32x4 v;
    v.x = (unsigned)f2bf(a.x) | ((unsigned)f2bf(a.y) << 16);
    v.y = (unsigned)f2bf(a.z) | ((unsigned)f2bf(a.w) << 16);
    v.z = (unsigned)f2bf(b.x) | ((unsigned)f2bf(b.y) << 16);
    v.w = (unsigned)f2bf(b.z) | ((unsigned)f2bf(b.w) << 16);
    return v;
}

__device__ __forceinline__ float4 neg4(float4 v) {
    return make_float4(-v.x, -v.y, -v.z, -v.w);
}

__device__ __forceinline__ void async16(const void* g, void* l) {
    __builtin_amdgcn_global_load_lds(
        (const __attribute__((address_space(1))) unsigned int*)g,
        (__attribute__((address_space(3))) unsigned int*)l,
        16, 0, 0);
}

__device__ __forceinline__ float sigm(float x) { return 1.0f / (1.0f + __expf(-x)); }
__device__ __forceinline__ float tanh_(float x) {
    float e = __expf(2.0f * x);          // |x| <~ 10 here, no overflow
    return (e - 1.0f) / (e + 1.0f);
}

// ------------------ merged pack: X rows + W (signs folded) + bias -----------
__global__ __launch_bounds__(256) void pack_all(
    const float* __restrict__ input, const float* __restrict__ hx,
    const float* __restrict__ Uw_r, const float* __restrict__ Uw_i,
    const float* __restrict__ Ww_r, const float* __restrict__ Ww_i,
    const float* __restrict__ Ub_r, const float* __restrict__ Ub_i,
    const float* __restrict__ Wb_r, const float* __restrict__ Wb_i,
    unsigned short* __restrict__ Xb, unsigned short* __restrict__ Wb16,
    float* __restrict__ biasp) {
    int bid = blockIdx.x;
    if (bid < 8192) {
        // ---- pack X = [input | h_x] rows ----
        int idx = bid * 256 + threadIdx.x;          // 2,097,152 chunks of 8
        int r    = idx >> 9;                        // row 0..4095
        int gcol = (idx & 511) * 8;                 // 0..4088
        const float* src = (gcol < 2048) ? (input + (size_t)r * 2048 + gcol)
                                         : (hx    + (size_t)r * 2048 + (gcol - 2048));
        float4 f0 = *(const float4*)src;
        float4 f1 = *(const float4*)(src + 4);
        *(u32x4*)(Xb + (size_t)idx * 8) = pack8(f0, f1);
    } else {
        // ---- pack W row-pairs + bias ----
        int idx = (bid - 8192) * 256 + threadIdx.x; // 2,097,152
        int np = idx >> 9;                          // o*4 + g, 0..4095
        int c8 = idx & 511;
        int k  = c8 * 8;                            // 0..4088
        int o = np >> 2, g = np & 3;
        int q = k >> 10, d = k & 1023;              // k-quarter, offset within
        size_t sidx = (size_t)g * (1024 * 1024) + (size_t)o * 1024 + d;
        const float* srcR = (q < 2 ? Uw_r : Ww_r) + sidx;
        const float* srcI = (q < 2 ? Uw_i : Ww_i) + sidx;
        float4 r0 = *(const float4*)srcR; float4 r1 = *(const float4*)(srcR + 4);
        float4 i0 = *(const float4*)srcI; float4 i1 = *(const float4*)(srcI + 4);
        int n0 = o * 8 + g * 2;
        u32x4 p0, p1;
        if (q & 1) { p0 = pack8(neg4(i0), neg4(i1)); p1 = pack8(r0, r1); }
        else       { p0 = pack8(r0, r1);             p1 = pack8(i0, i1); }
        *(u32x4*)(Wb16 + (size_t)n0 * KDIM + k)       = p0;
        *(u32x4*)(Wb16 + (size_t)(n0 + 1) * KDIM + k) = p1;
        if (c8 == 0) {
            size_t bi = (size_t)g * 1024 + o;
            biasp[n0]     = Ub_r[bi] + Wb_r[bi];
            biasp[n0 + 1] = Ub_i[bi] + Wb_i[bi];
        }
    }
}

// ------------------------- GEMM + fused epilogue ----------------------------
// block: 512 threads (8 waves, 2Mx4N), C-tile 256x256, BK=64, 16x16x32 MFMA.
// LDS: 2 buffers x (A 32KB + B 32KB) = 128 KiB (dynamic; attribute set on host).
// Per-wave output 128x64 -> acc[8][4] f32x4 (128 regs, AGPR-eligible).
// PLAIN launch_bounds — see R5 note above. Occupancy is LDS-bound (1 blk/CU).
__global__ __launch_bounds__(512) void clstm_gemm(
    const unsigned short* __restrict__ Xb,    // 4096 x 4096 bf16
    const unsigned short* __restrict__ Wb,    // 8192 x 4096 bf16
    const float* __restrict__ biasp,          // 8192
    const float* __restrict__ c_x,            // 4096 x 2048 fp32
    float* __restrict__ out) {
    extern __shared__ char smem[];            // 131072 bytes

    const int tid  = threadIdx.x;
    const int lane = tid & 63;
    const int wave = tid >> 6;                // 0..7
    const int wm = wave >> 2, wn = wave & 3;  // 2 x 4 wave grid
    const int quad = lane >> 4, col16 = lane & 15;

    // XCD-contiguous block swizzle: nwg=512 (8|512 -> bijective), then 4x8
    // supertiles so 32 consecutive swz share 4 A-panels + 8 B-panels.
    const int bid = blockIdx.x;
    const int swz = (bid & 7) * 64 + (bid >> 3);
    const int st = swz >> 5, wi = swz & 31;
    const int mtile = (st & 3) * 4 + (wi & 3);      // 0..15
    const int ntile = (st >> 2) * 8 + (wi >> 2);    // 0..31

    // staging: per K-tile 8 global_load_lds x 16B per thread (4 A + 4 B).
    // chunk id for load i = i*512 + tid -> LDS row id>>3, slot id&7 (linear
    // dest); global source pre-swizzled: chunk fetched = slot ^ (row&7).
    const int srow  = tid >> 3;               // 0..63
    const int sslot = tid & 7;
    const unsigned short* pa[4];
    const unsigned short* pb[4];
#pragma unroll
    for (int i = 0; i < 4; ++i) {
        const int rowA = i * 64 + srow;       // 0..255
        const int c = sslot ^ (rowA & 7);
        pa[i] = Xb + (size_t)(mtile * 256 + rowA) * KDIM + c * 8;
        pb[i] = Wb + (size_t)(ntile * 256 + rowA) * KDIM + c * 8;
    }

    f32x4 acc[8][4] = {};

    // prologue: stage tile 0 into buf0
#pragma unroll
    for (int i = 0; i < 4; ++i) {
        async16(pa[i], smem + i * 8192 + wave * 1024);
        async16(pb[i], smem + 32768 + i * 8192 + wave * 1024);
        pa[i] += 64; pb[i] += 64;
    }

    const int rA0 = wm * 128 + col16;         // + p*32 + f*16
    const int rB0 = wn * 64 + col16;          // + n*16

#pragma unroll 2
    for (int kt = 0; kt < 64; ++kt) {
        char* sA  = smem + (kt & 1) * 65536;
        char* sB  = sA + 32768;
        char* sAn = smem + (((kt & 1) ^ 1)) * 65536;
        char* sBn = sAn + 32768;

        // Issue next tile's 8 loads FIRST (into the buffer whose readers all
        // finished before tile kt-1's final barrier), then counted wait:
        // vmcnt(8) completes the 8 OLDEST (= tile kt's own loads, issued one
        // full tile of MFMA ago) while the 8 new ones stay in flight.
        if (kt < 63) {
#pragma unroll
            for (int i = 0; i < 4; ++i) {
                async16(pa[i], sAn + i * 8192 + wave * 1024);
                async16(pb[i], sBn + i * 8192 + wave * 1024);
                pa[i] += 64; pb[i] += 64;
            }
            asm volatile("s_waitcnt vmcnt(8)" ::: "memory");
        } else {
            asm volatile("s_waitcnt vmcnt(0)" ::: "memory");
        }
        __builtin_amdgcn_s_barrier();         // all waves' tile-kt slices in LDS

        // B fragments for the whole K-tile (8 x ds_read_b128), reused by all
        // 4 phases: 4 N-frags x 2 k-slices.
        bf16x8 bfr[4][2];
#pragma unroll
        for (int n = 0; n < 4; ++n)
#pragma unroll
            for (int ks = 0; ks < 2; ++ks) {
                const int r = rB0 + n * 16;
                const int ch = (ks * 4 + quad) ^ (r & 7);
                bfr[n][ks] = *(const bf16x8*)(sB + r * 128 + ch * 16);
            }

        // 4 phases: phase p computes M-frags {2p, 2p+1} x all 4 N-frags x K=64
#pragma unroll
        for (int p = 0; p < 4; ++p) {
            bf16x8 af[2][2];
#pragma unroll
            for (int f = 0; f < 2; ++f)
#pragma unroll
                for (int ks = 0; ks < 2; ++ks) {
                    const int r = rA0 + p * 32 + f * 16;
                    const int ch = (ks * 4 + quad) ^ (r & 7);
                    af[f][ks] = *(const bf16x8*)(sA + r * 128 + ch * 16);
                }
            __builtin_amdgcn_s_barrier();     // phase-lockstep (no waitcnt)
            __builtin_amdgcn_s_setprio(1);
#pragma unroll
            for (int f = 0; f < 2; ++f)
#pragma unroll
                for (int n = 0; n < 4; ++n) {
                    acc[p * 2 + f][n] = __builtin_amdgcn_mfma_f32_16x16x32_bf16(
                        af[f][0], bfr[n][0], acc[p * 2 + f][n], 0, 0, 0);
                    acc[p * 2 + f][n] = __builtin_amdgcn_mfma_f32_16x16x32_bf16(
                        af[f][1], bfr[n][1], acc[p * 2 + f][n], 0, 0, 0);
                }
            __builtin_amdgcn_s_setprio(0);
            __builtin_amdgcn_s_barrier();
        }
    }

    // ---- epilogue: per-wave LDS round trip, C-layout -> (row, o) layout ----
    // Wave tile = 128 rows x 64 cols. 8 passes of (32 rows x 32 cols):
    // pass = seg (0..3, row segment) x h (0..1, col half). zs is WAVE-PRIVATE
    // (disjoint 8KB regions): one barrier total, then intra-wave ordering only.
    __syncthreads();                          // all K-loop LDS traffic done
    float* zs = (float*)(smem + wave * 8192); // 32 rows x 40 f32 = 5120B used
    const float* bp = biasp + ntile * 256 + wn * 64;
    const int o_idx = lane & 3;
    const int rgrp  = lane >> 2;              // 0..15

    for (int pass = 0; pass < 8; ++pass) {
        const int seg = pass >> 1;            // row segment: acc mf = seg*2 + {0,1}
        const int h   = pass & 1;             // col half:   acc nf = h*2 + {0,1}
#pragma unroll
        for (int mf2 = 0; mf2 < 2; ++mf2)
#pragma unroll
            for (int tl = 0; tl < 2; ++tl) {
                int nf = h * 2 + tl;
                int colz = tl * 16 + col16;
#pragma unroll
                for (int r = 0; r < 4; ++r)
                    zs[(mf2 * 16 + quad * 4 + r) * 40 + colz] = acc[seg * 2 + mf2][nf][r];
            }
        // intra-wave RAW through LDS: compiler inserts lgkmcnt wait

        float4 bb0 = *(const float4*)(bp + h * 32 + o_idx * 8);
        float4 bb1 = *(const float4*)(bp + h * 32 + o_idx * 8 + 4);
        int o_glob = ntile * 32 + wn * 8 + h * 4 + o_idx;

#pragma unroll
        for (int t = 0; t < 2; ++t) {
            int rowz = rgrp + t * 16;         // 0..31 within segment
            const float* zp = zs + rowz * 40 + o_idx * 8;
            float4 z0 = *(const float4*)zp;
            float4 z1 = *(const float4*)(zp + 4);
            int b = mtile * 256 + wm * 128 + seg * 32 + rowz;

            float fr = sigm(z0.x + bb0.x), fi = sigm(z0.y + bb0.y);
            float ir = sigm(z0.z + bb0.z), ii = sigm(z0.w + bb0.w);
            float ar = tanh_(z1.x + bb1.x), ai = tanh_(z1.y + bb1.y);
            float og_r = sigm(z1.z + bb1.z), og_i = sigm(z1.w + bb1.w);

            float cr = c_x[(size_t)b * 2048 + o_glob];
            float ci = c_x[(size_t)b * 2048 + 1024 + o_glob];

            float ct_r = (cr * fr - ci * fi) + (ar * ir - ai * ii);
            float ct_i = (cr * fi + ci * fr) + (ar * ii + ai * ir);
            float tr = tanh_(ct_r), ti = tanh_(ct_i);
            float ht_r = og_r * tr - og_i * ti;
            float ht_i = og_r * ti + og_i * tr;

            out[(size_t)b * 2048 + o_glob]               = ht_r;
            out[(size_t)b * 2048 + 1024 + o_glob]        = ht_i;
            out[HOFF + (size_t)b * 2048 + o_glob]        = ct_r;
            out[HOFF + (size_t)b * 2048 + 1024 + o_glob] = ct_i;
        }
        if (pass < 7) __builtin_amdgcn_s_waitcnt(0);  // drain LDS reads before
                                                      // overwriting wave-private zs
    }
}

// ---------------------------------------------------------------------------
extern "C" void kernel_launch(void* const* d_in, const int* in_sizes, int n_in,
                              void* d_out, int out_size, void* d_ws, size_t ws_size,
                              hipStream_t stream) {
    const float* input = (const float*)d_in[0];
    const float* h_x   = (const float*)d_in[1];
    const float* c_x   = (const float*)d_in[2];
    const float* Uw_r  = (const float*)d_in[3];
    const float* Uw_i  = (const float*)d_in[4];
    const float* Ub_r  = (const float*)d_in[5];
    const float* Ub_i  = (const float*)d_in[6];
    const float* Ww_r  = (const float*)d_in[7];
    const float* Ww_i  = (const float*)d_in[8];
    const float* Wb_r  = (const float*)d_in[9];
    const float* Wb_i  = (const float*)d_in[10];
    float* out = (float*)d_out;

    // ws layout: X bf16 (32MB) | Wbig bf16 (64MB) | bias fp32 (32KB)  ~= 96MB
    unsigned short* Xb   = (unsigned short*)d_ws;
    unsigned short* Wb16 = Xb + (size_t)4096 * 4096;
    float* biasp = (float*)(Wb16 + (size_t)8192 * 4096);

    static bool s_attr = false;               // host-side, not a stream op:
    if (!s_attr) {                            // graph-capture safe
        hipFuncSetAttribute((const void*)clstm_gemm,
                            hipFuncAttributeMaxDynamicSharedMemorySize, 131072);
        s_attr = true;
    }

    pack_all<<<16384, 256, 0, stream>>>(input, h_x, Uw_r, Uw_i, Ww_r, Ww_i,
                                        Ub_r, Ub_i, Wb_r, Wb_i, Xb, Wb16, biasp);
    clstm_gemm<<<512, 512, 131072, stream>>>(Xb, Wb16, biasp, c_x, out);
}

// Round 3
// 457.543 us; speedup vs baseline: 1.2226x; 1.2226x over previous
//
#include <hip/hip_runtime.h>
#include <cstddef>

// ---------------------------------------------------------------------------
// CLSTMCell fused as one bf16 GEMM + epilogue.
//   X (4096 x 4096)  = [xr | xi | hr | hi] rows  (bf16, packed in ws)
//   W (8192 x 4096)  rows n = o*8 + g*2 + p, k-quarters [UwR,-UwI,WwR,-WwI] (p=0)
//                                            [UwI, UwR, WwI, WwR]           (p=1)
//   z = X @ W^T + bias ; epilogue: gates -> c_t, h_t  (fp32 out)
//
// R4: 256^2 8-wave counted-vmcnt schedule (m201 template): BM=BN=256 BK=64,
//   8 waves (2Mx4N), 128KiB double-buffered LDS. Per K-tile: issue next
//   tile's 8 global_load_lds -> s_waitcnt vmcnt(8) (never drain to 0 in the
//   loop) -> 4 phases of {4x ds_read_b128 A-frags, barrier, 16 MFMA under
//   setprio(1), barrier}. B-frags (8 ds_reads) once per tile.
//
// R5/R6 post-mortem (CRITICAL, do not regress):
//   * launch_bounds 2nd arg is a red herring for 512-thr blocks: (512,2) and
//     plain (512) compile IDENTICALLY (min waves/EU is already 2).
//   * The real bug was rule #20: the epilogue pass-loop was NOT unrolled, so
//     `acc[seg*2+mf2][nf][r]` with runtime `seg` was a dynamic index into an
//     ext_vector array -> SROA fails -> acc[8][4] (512B/thread) lives on the
//     STACK: 134MB scratch writes + 134MB reads per dispatch (WRITE_SIZE 380
//     vs 135 ideal), plus scratch churn evicting X/W panels from L2 under
//     concurrent blocks' K-loops. Fix: #pragma unroll on the pass loop so
//     every acc index is compile-time. Verify: WRITE_SIZE ~135MB.
// ---------------------------------------------------------------------------

typedef short bf16x8 __attribute__((ext_vector_type(8)));   // 8 bf16 (4 VGPRs)
typedef float f32x4  __attribute__((ext_vector_type(4)));
typedef unsigned int u32x4 __attribute__((ext_vector_type(4)));

static constexpr int KDIM = 4096;
static constexpr size_t HOFF = (size_t)4096 * 2048;   // out offset of c_t

__device__ __forceinline__ unsigned short f2bf(float f) {
    unsigned u = __float_as_uint(f);
    u += 0x7FFF + ((u >> 16) & 1);      // RNE
    return (unsigned short)(u >> 16);
}

__device__ __forceinline__ u32x4 pack8(float4 a, float4 b) {
    u32x4 v;
    v.x = (unsigned)f2bf(a.x) | ((unsigned)f2bf(a.y) << 16);
    v.y = (unsigned)f2bf(a.z) | ((unsigned)f2bf(a.w) << 16);
    v.z = (unsigned)f2bf(b.x) | ((unsigned)f2bf(b.y) << 16);
    v.w = (unsigned)f2bf(b.z) | ((unsigned)f2bf(b.w) << 16);
    return v;
}

__device__ __forceinline__ float4 neg4(float4 v) {
    return make_float4(-v.x, -v.y, -v.z, -v.w);
}

__device__ __forceinline__ void async16(const void* g, void* l) {
    __builtin_amdgcn_global_load_lds(
        (const __attribute__((address_space(1))) unsigned int*)g,
        (__attribute__((address_space(3))) unsigned int*)l,
        16, 0, 0);
}

__device__ __forceinline__ float sigm(float x) { return 1.0f / (1.0f + __expf(-x)); }
__device__ __forceinline__ float tanh_(float x) {
    float e = __expf(2.0f * x);          // |x| <~ 10 here, no overflow
    return (e - 1.0f) / (e + 1.0f);
}

// ------------------ merged pack: X rows + W (signs folded) + bias -----------
__global__ __launch_bounds__(256) void pack_all(
    const float* __restrict__ input, const float* __restrict__ hx,
    const float* __restrict__ Uw_r, const float* __restrict__ Uw_i,
    const float* __restrict__ Ww_r, const float* __restrict__ Ww_i,
    const float* __restrict__ Ub_r, const float* __restrict__ Ub_i,
    const float* __restrict__ Wb_r, const float* __restrict__ Wb_i,
    unsigned short* __restrict__ Xb, unsigned short* __restrict__ Wb16,
    float* __restrict__ biasp) {
    int bid = blockIdx.x;
    if (bid < 8192) {
        // ---- pack X = [input | h_x] rows ----
        int idx = bid * 256 + threadIdx.x;          // 2,097,152 chunks of 8
        int r    = idx >> 9;                        // row 0..4095
        int gcol = (idx & 511) * 8;                 // 0..4088
        const float* src = (gcol < 2048) ? (input + (size_t)r * 2048 + gcol)
                                         : (hx    + (size_t)r * 2048 + (gcol - 2048));
        float4 f0 = *(const float4*)src;
        float4 f1 = *(const float4*)(src + 4);
        *(u32x4*)(Xb + (size_t)idx * 8) = pack8(f0, f1);
    } else {
        // ---- pack W row-pairs + bias ----
        int idx = (bid - 8192) * 256 + threadIdx.x; // 2,097,152
        int np = idx >> 9;                          // o*4 + g, 0..4095
        int c8 = idx & 511;
        int k  = c8 * 8;                            // 0..4088
        int o = np >> 2, g = np & 3;
        int q = k >> 10, d = k & 1023;              // k-quarter, offset within
        size_t sidx = (size_t)g * (1024 * 1024) + (size_t)o * 1024 + d;
        const float* srcR = (q < 2 ? Uw_r : Ww_r) + sidx;
        const float* srcI = (q < 2 ? Uw_i : Ww_i) + sidx;
        float4 r0 = *(const float4*)srcR; float4 r1 = *(const float4*)(srcR + 4);
        float4 i0 = *(const float4*)srcI; float4 i1 = *(const float4*)(srcI + 4);
        int n0 = o * 8 + g * 2;
        u32x4 p0, p1;
        if (q & 1) { p0 = pack8(neg4(i0), neg4(i1)); p1 = pack8(r0, r1); }
        else       { p0 = pack8(r0, r1);             p1 = pack8(i0, i1); }
        *(u32x4*)(Wb16 + (size_t)n0 * KDIM + k)       = p0;
        *(u32x4*)(Wb16 + (size_t)(n0 + 1) * KDIM + k) = p1;
        if (c8 == 0) {
            size_t bi = (size_t)g * 1024 + o;
            biasp[n0]     = Ub_r[bi] + Wb_r[bi];
            biasp[n0 + 1] = Ub_i[bi] + Wb_i[bi];
        }
    }
}

// ------------------------- GEMM + fused epilogue ----------------------------
// block: 512 threads (8 waves, 2Mx4N), C-tile 256x256, BK=64, 16x16x32 MFMA.
// LDS: 2 buffers x (A 32KB + B 32KB) = 128 KiB (dynamic; attribute set on host).
// Per-wave output 128x64 -> acc[8][4] f32x4 (128 regs, AGPR-eligible).
__global__ __launch_bounds__(512) void clstm_gemm(
    const unsigned short* __restrict__ Xb,    // 4096 x 4096 bf16
    const unsigned short* __restrict__ Wb,    // 8192 x 4096 bf16
    const float* __restrict__ biasp,          // 8192
    const float* __restrict__ c_x,            // 4096 x 2048 fp32
    float* __restrict__ out) {
    extern __shared__ char smem[];            // 131072 bytes

    const int tid  = threadIdx.x;
    const int lane = tid & 63;
    const int wave = tid >> 6;                // 0..7
    const int wm = wave >> 2, wn = wave & 3;  // 2 x 4 wave grid
    const int quad = lane >> 4, col16 = lane & 15;

    // XCD-contiguous block swizzle: nwg=512 (8|512 -> bijective), then 4x8
    // supertiles so 32 consecutive swz share 4 A-panels + 8 B-panels.
    const int bid = blockIdx.x;
    const int swz = (bid & 7) * 64 + (bid >> 3);
    const int st = swz >> 5, wi = swz & 31;
    const int mtile = (st & 3) * 4 + (wi & 3);      // 0..15
    const int ntile = (st >> 2) * 8 + (wi >> 2);    // 0..31

    // staging: per K-tile 8 global_load_lds x 16B per thread (4 A + 4 B).
    // chunk id for load i = i*512 + tid -> LDS row id>>3, slot id&7 (linear
    // dest); global source pre-swizzled: chunk fetched = slot ^ (row&7).
    const int srow  = tid >> 3;               // 0..63
    const int sslot = tid & 7;
    const unsigned short* pa[4];
    const unsigned short* pb[4];
#pragma unroll
    for (int i = 0; i < 4; ++i) {
        const int rowA = i * 64 + srow;       // 0..255
        const int c = sslot ^ (rowA & 7);
        pa[i] = Xb + (size_t)(mtile * 256 + rowA) * KDIM + c * 8;
        pb[i] = Wb + (size_t)(ntile * 256 + rowA) * KDIM + c * 8;
    }

    f32x4 acc[8][4] = {};

    // prologue: stage tile 0 into buf0
#pragma unroll
    for (int i = 0; i < 4; ++i) {
        async16(pa[i], smem + i * 8192 + wave * 1024);
        async16(pb[i], smem + 32768 + i * 8192 + wave * 1024);
        pa[i] += 64; pb[i] += 64;
    }

    const int rA0 = wm * 128 + col16;         // + p*32 + f*16
    const int rB0 = wn * 64 + col16;          // + n*16

#pragma unroll 2
    for (int kt = 0; kt < 64; ++kt) {
        char* sA  = smem + (kt & 1) * 65536;
        char* sB  = sA + 32768;
        char* sAn = smem + (((kt & 1) ^ 1)) * 65536;
        char* sBn = sAn + 32768;

        // Issue next tile's 8 loads FIRST (into the buffer whose readers all
        // finished before tile kt-1's final barrier), then counted wait:
        // vmcnt(8) completes the 8 OLDEST (= tile kt's own loads, issued one
        // full tile of MFMA ago) while the 8 new ones stay in flight.
        if (kt < 63) {
#pragma unroll
            for (int i = 0; i < 4; ++i) {
                async16(pa[i], sAn + i * 8192 + wave * 1024);
                async16(pb[i], sBn + i * 8192 + wave * 1024);
                pa[i] += 64; pb[i] += 64;
            }
            asm volatile("s_waitcnt vmcnt(8)" ::: "memory");
        } else {
            asm volatile("s_waitcnt vmcnt(0)" ::: "memory");
        }
        __builtin_amdgcn_s_barrier();         // all waves' tile-kt slices in LDS

        // B fragments for the whole K-tile (8 x ds_read_b128), reused by all
        // 4 phases: 4 N-frags x 2 k-slices.
        bf16x8 bfr[4][2];
#pragma unroll
        for (int n = 0; n < 4; ++n)
#pragma unroll
            for (int ks = 0; ks < 2; ++ks) {
                const int r = rB0 + n * 16;
                const int ch = (ks * 4 + quad) ^ (r & 7);
                bfr[n][ks] = *(const bf16x8*)(sB + r * 128 + ch * 16);
            }

        // 4 phases: phase p computes M-frags {2p, 2p+1} x all 4 N-frags x K=64
#pragma unroll
        for (int p = 0; p < 4; ++p) {
            bf16x8 af[2][2];
#pragma unroll
            for (int f = 0; f < 2; ++f)
#pragma unroll
                for (int ks = 0; ks < 2; ++ks) {
                    const int r = rA0 + p * 32 + f * 16;
                    const int ch = (ks * 4 + quad) ^ (r & 7);
                    af[f][ks] = *(const bf16x8*)(sA + r * 128 + ch * 16);
                }
            __builtin_amdgcn_s_barrier();     // phase-lockstep (no waitcnt)
            __builtin_amdgcn_s_setprio(1);
#pragma unroll
            for (int f = 0; f < 2; ++f)
#pragma unroll
                for (int n = 0; n < 4; ++n) {
                    acc[p * 2 + f][n] = __builtin_amdgcn_mfma_f32_16x16x32_bf16(
                        af[f][0], bfr[n][0], acc[p * 2 + f][n], 0, 0, 0);
                    acc[p * 2 + f][n] = __builtin_amdgcn_mfma_f32_16x16x32_bf16(
                        af[f][1], bfr[n][1], acc[p * 2 + f][n], 0, 0, 0);
                }
            __builtin_amdgcn_s_setprio(0);
            __builtin_amdgcn_s_barrier();
        }
    }

    // ---- epilogue: per-wave LDS round trip, C-layout -> (row, o) layout ----
    // Wave tile = 128 rows x 64 cols. 8 passes of (32 rows x 32 cols):
    // pass = seg (0..3, row segment) x h (0..1, col half). zs is WAVE-PRIVATE
    // (disjoint 8KB regions): one barrier total, then intra-wave ordering only.
    // FULLY UNROLLED (rule #20): every acc index must be compile-time or the
    // whole acc array is demoted to scratch (134MB/dispatch round trip).
    __syncthreads();                          // all K-loop LDS traffic done
    float* zs = (float*)(smem + wave * 8192); // 32 rows x 40 f32 = 5120B used
    const float* bp = biasp + ntile * 256 + wn * 64;
    const int o_idx = lane & 3;
    const int rgrp  = lane >> 2;              // 0..15

#pragma unroll
    for (int pass = 0; pass < 8; ++pass) {
        const int seg = pass >> 1;            // row segment: acc mf = seg*2 + {0,1}
        const int h   = pass & 1;             // col half:   acc nf = h*2 + {0,1}
#pragma unroll
        for (int mf2 = 0; mf2 < 2; ++mf2)
#pragma unroll
            for (int tl = 0; tl < 2; ++tl) {
                int nf = h * 2 + tl;
                int colz = tl * 16 + col16;
#pragma unroll
                for (int r = 0; r < 4; ++r)
                    zs[(mf2 * 16 + quad * 4 + r) * 40 + colz] = acc[seg * 2 + mf2][nf][r];
            }
        // intra-wave RAW through LDS: compiler inserts lgkmcnt wait

        float4 bb0 = *(const float4*)(bp + h * 32 + o_idx * 8);
        float4 bb1 = *(const float4*)(bp + h * 32 + o_idx * 8 + 4);
        int o_glob = ntile * 32 + wn * 8 + h * 4 + o_idx;

#pragma unroll
        for (int t = 0; t < 2; ++t) {
            int rowz = rgrp + t * 16;         // 0..31 within segment
            const float* zp = zs + rowz * 40 + o_idx * 8;
            float4 z0 = *(const float4*)zp;
            float4 z1 = *(const float4*)(zp + 4);
            int b = mtile * 256 + wm * 128 + seg * 32 + rowz;

            float fr = sigm(z0.x + bb0.x), fi = sigm(z0.y + bb0.y);
            float ir = sigm(z0.z + bb0.z), ii = sigm(z0.w + bb0.w);
            float ar = tanh_(z1.x + bb1.x), ai = tanh_(z1.y + bb1.y);
            float og_r = sigm(z1.z + bb1.z), og_i = sigm(z1.w + bb1.w);

            float cr = c_x[(size_t)b * 2048 + o_glob];
            float ci = c_x[(size_t)b * 2048 + 1024 + o_glob];

            float ct_r = (cr * fr - ci * fi) + (ar * ir - ai * ii);
            float ct_i = (cr * fi + ci * fr) + (ar * ii + ai * ir);
            float tr = tanh_(ct_r), ti = tanh_(ct_i);
            float ht_r = og_r * tr - og_i * ti;
            float ht_i = og_r * ti + og_i * tr;

            out[(size_t)b * 2048 + o_glob]               = ht_r;
            out[(size_t)b * 2048 + 1024 + o_glob]        = ht_i;
            out[HOFF + (size_t)b * 2048 + o_glob]        = ct_r;
            out[HOFF + (size_t)b * 2048 + 1024 + o_glob] = ct_i;
        }
        if (pass < 7)                          // drain zs reads before next pass
            asm volatile("s_waitcnt lgkmcnt(0)" ::: "memory");  // overwrites zs
    }
}

// ---------------------------------------------------------------------------
extern "C" void kernel_launch(void* const* d_in, const int* in_sizes, int n_in,
                              void* d_out, int out_size, void* d_ws, size_t ws_size,
                              hipStream_t stream) {
    const float* input = (const float*)d_in[0];
    const float* h_x   = (const float*)d_in[1];
    const float* c_x   = (const float*)d_in[2];
    const float* Uw_r  = (const float*)d_in[3];
    const float* Uw_i  = (const float*)d_in[4];
    const float* Ub_r  = (const float*)d_in[5];
    const float* Ub_i  = (const float*)d_in[6];
    const float* Ww_r  = (const float*)d_in[7];
    const float* Ww_i  = (const float*)d_in[8];
    const float* Wb_r  = (const float*)d_in[9];
    const float* Wb_i  = (const float*)d_in[10];
    float* out = (float*)d_out;

    // ws layout: X bf16 (32MB) | Wbig bf16 (64MB) | bias fp32 (32KB)  ~= 96MB
    unsigned short* Xb   = (unsigned short*)d_ws;
    unsigned short* Wb16 = Xb + (size_t)4096 * 4096;
    float* biasp = (float*)(Wb16 + (size_t)8192 * 4096);

    static bool s_attr = false;               // host-side, not a stream op:
    if (!s_attr) {                            // graph-capture safe
        hipFuncSetAttribute((const void*)clstm_gemm,
                            hipFuncAttributeMaxDynamicSharedMemorySize, 131072);
        s_attr = true;
    }

    pack_all<<<16384, 256, 0, stream>>>(input, h_x, Uw_r, Uw_i, Ww_r, Ww_i,
                                        Ub_r, Ub_i, Wb_r, Wb_i, Xb, Wb16, biasp);
    clstm_gemm<<<512, 512, 131072, stream>>>(Xb, Wb16, biasp, c_x, out);
}

// Round 4
// 433.017 us; speedup vs baseline: 1.2919x; 1.0566x over previous
//
#include <hip/hip_runtime.h>
#include <cstddef>

// ---------------------------------------------------------------------------
// CLSTMCell fused as one bf16 GEMM + epilogue.
//   X (4096 x 4096)  = [xr | xi | hr | hi] rows  (bf16, packed in ws)
//   W (8192 x 4096)  rows n = o*8 + g*2 + p, k-quarters [UwR,-UwI,WwR,-WwI] (p=0)
//                                            [UwI, UwR, WwI, WwR]           (p=1)
//   z = X @ W^T + bias ; epilogue: gates -> c_t, h_t  (fp32 out)
//
// R7: K-loop restructured as a 1-phase register software pipeline.
//   R6 analysis: per-CU/K-tile floors are MFMA 2,483 cyc, LDS 1,540 cyc;
//   measured 5,600 cyc = STRICT ALTERNATION (reads->barrier->MFMA-on-those-
//   reads->barrier serializes the LDS and matrix pipes into disjoint windows;
//   MfmaUtil 41% == 2483/5600). Fix: phase p issues ds_reads for phase p+1's
//   A-frags (ping-pong af[2][2][2], statically indexed - rule #20) and runs
//   phase p's MFMAs on frags read LAST phase (already retired -> compiler
//   emits lgkmcnt(4), not a drain). LDS pipe now runs concurrently with the
//   matrix pipe. ONE barrier per K-tile (after vmcnt(0) at the boundary;
//   loads were issued a full tile ~4000cyc earlier, so the drain is free).
//   Stage issue spread 2/phase. Race analysis: stages for kt+1 target buffer
//   ^1; its kt-1 readers retired reads (lgkm before their phase-3 MFMAs)
//   before passing the boundary barrier that precedes any kt stage issue.
//
// R5/R6 post-mortem (do not regress):
//   * rule #20: EVERY acc/af index must be compile-time (full unroll) or the
//     array demotes to scratch (R5: 134MB/dispatch scratch round trip).
//   * launch_bounds 2nd arg for 512-thr blocks is a no-op; keep plain (512).
// ---------------------------------------------------------------------------

typedef short bf16x8 __attribute__((ext_vector_type(8)));   // 8 bf16 (4 VGPRs)
typedef float f32x4  __attribute__((ext_vector_type(4)));
typedef unsigned int u32x4 __attribute__((ext_vector_type(4)));

static constexpr int KDIM = 4096;
static constexpr size_t HOFF = (size_t)4096 * 2048;   // out offset of c_t

__device__ __forceinline__ unsigned short f2bf(float f) {
    unsigned u = __float_as_uint(f);
    u += 0x7FFF + ((u >> 16) & 1);      // RNE
    return (unsigned short)(u >> 16);
}

__device__ __forceinline__ u32x4 pack8(float4 a, float4 b) {
    u32x4 v;
    v.x = (unsigned)f2bf(a.x) | ((unsigned)f2bf(a.y) << 16);
    v.y = (unsigned)f2bf(a.z) | ((unsigned)f2bf(a.w) << 16);
    v.z = (unsigned)f2bf(b.x) | ((unsigned)f2bf(b.y) << 16);
    v.w = (unsigned)f2bf(b.z) | ((unsigned)f2bf(b.w) << 16);
    return v;
}

__device__ __forceinline__ float4 neg4(float4 v) {
    return make_float4(-v.x, -v.y, -v.z, -v.w);
}

__device__ __forceinline__ void async16(const void* g, void* l) {
    __builtin_amdgcn_global_load_lds(
        (const __attribute__((address_space(1))) unsigned int*)g,
        (__attribute__((address_space(3))) unsigned int*)l,
        16, 0, 0);
}

__device__ __forceinline__ float sigm(float x) { return 1.0f / (1.0f + __expf(-x)); }
__device__ __forceinline__ float tanh_(float x) {
    float e = __expf(2.0f * x);          // |x| <~ 10 here, no overflow
    return (e - 1.0f) / (e + 1.0f);
}

// ------------------ merged pack: X rows + W (signs folded) + bias -----------
__global__ __launch_bounds__(256) void pack_all(
    const float* __restrict__ input, const float* __restrict__ hx,
    const float* __restrict__ Uw_r, const float* __restrict__ Uw_i,
    const float* __restrict__ Ww_r, const float* __restrict__ Ww_i,
    const float* __restrict__ Ub_r, const float* __restrict__ Ub_i,
    const float* __restrict__ Wb_r, const float* __restrict__ Wb_i,
    unsigned short* __restrict__ Xb, unsigned short* __restrict__ Wb16,
    float* __restrict__ biasp) {
    int bid = blockIdx.x;
    if (bid < 8192) {
        // ---- pack X = [input | h_x] rows ----
        int idx = bid * 256 + threadIdx.x;          // 2,097,152 chunks of 8
        int r    = idx >> 9;                        // row 0..4095
        int gcol = (idx & 511) * 8;                 // 0..4088
        const float* src = (gcol < 2048) ? (input + (size_t)r * 2048 + gcol)
                                         : (hx    + (size_t)r * 2048 + (gcol - 2048));
        float4 f0 = *(const float4*)src;
        float4 f1 = *(const float4*)(src + 4);
        *(u32x4*)(Xb + (size_t)idx * 8) = pack8(f0, f1);
    } else {
        // ---- pack W row-pairs + bias ----
        int idx = (bid - 8192) * 256 + threadIdx.x; // 2,097,152
        int np = idx >> 9;                          // o*4 + g, 0..4095
        int c8 = idx & 511;
        int k  = c8 * 8;                            // 0..4088
        int o = np >> 2, g = np & 3;
        int q = k >> 10, d = k & 1023;              // k-quarter, offset within
        size_t sidx = (size_t)g * (1024 * 1024) + (size_t)o * 1024 + d;
        const float* srcR = (q < 2 ? Uw_r : Ww_r) + sidx;
        const float* srcI = (q < 2 ? Uw_i : Ww_i) + sidx;
        float4 r0 = *(const float4*)srcR; float4 r1 = *(const float4*)(srcR + 4);
        float4 i0 = *(const float4*)srcI; float4 i1 = *(const float4*)(srcI + 4);
        int n0 = o * 8 + g * 2;
        u32x4 p0, p1;
        if (q & 1) { p0 = pack8(neg4(i0), neg4(i1)); p1 = pack8(r0, r1); }
        else       { p0 = pack8(r0, r1);             p1 = pack8(i0, i1); }
        *(u32x4*)(Wb16 + (size_t)n0 * KDIM + k)       = p0;
        *(u32x4*)(Wb16 + (size_t)(n0 + 1) * KDIM + k) = p1;
        if (c8 == 0) {
            size_t bi = (size_t)g * 1024 + o;
            biasp[n0]     = Ub_r[bi] + Wb_r[bi];
            biasp[n0 + 1] = Ub_i[bi] + Wb_i[bi];
        }
    }
}

// ------------------------- GEMM + fused epilogue ----------------------------
// block: 512 threads (8 waves, 2Mx4N), C-tile 256x256, BK=64, 16x16x32 MFMA.
// LDS: 2 buffers x (A 32KB + B 32KB) = 128 KiB (dynamic; attribute set on host).
// Per-wave output 128x64 -> acc[8][4] f32x4 (128 regs, AGPR-eligible).
__global__ __launch_bounds__(512) void clstm_gemm(
    const unsigned short* __restrict__ Xb,    // 4096 x 4096 bf16
    const unsigned short* __restrict__ Wb,    // 8192 x 4096 bf16
    const float* __restrict__ biasp,          // 8192
    const float* __restrict__ c_x,            // 4096 x 2048 fp32
    float* __restrict__ out) {
    extern __shared__ char smem[];            // 131072 bytes

    const int tid  = threadIdx.x;
    const int lane = tid & 63;
    const int wave = tid >> 6;                // 0..7
    const int wm = wave >> 2, wn = wave & 3;  // 2 x 4 wave grid
    const int quad = lane >> 4, col16 = lane & 15;

    // XCD-contiguous block swizzle: nwg=512 (8|512 -> bijective), then 4x8
    // supertiles so 32 consecutive swz share 4 A-panels + 8 B-panels.
    const int bid = blockIdx.x;
    const int swz = (bid & 7) * 64 + (bid >> 3);
    const int st = swz >> 5, wi = swz & 31;
    const int mtile = (st & 3) * 4 + (wi & 3);      // 0..15
    const int ntile = (st >> 2) * 8 + (wi >> 2);    // 0..31

    // staging: per K-tile 8 global_load_lds x 16B per thread (4 A + 4 B).
    // chunk id for load i = i*512 + tid -> LDS row id>>3, slot id&7 (linear
    // dest); global source pre-swizzled: chunk fetched = slot ^ (row&7).
    const int srow  = tid >> 3;               // 0..63
    const int sslot = tid & 7;
    const unsigned short* pa[4];
    const unsigned short* pb[4];
#pragma unroll
    for (int i = 0; i < 4; ++i) {
        const int rowA = i * 64 + srow;       // 0..255
        const int c = sslot ^ (rowA & 7);
        pa[i] = Xb + (size_t)(mtile * 256 + rowA) * KDIM + c * 8;
        pb[i] = Wb + (size_t)(ntile * 256 + rowA) * KDIM + c * 8;
    }

    f32x4 acc[8][4] = {};

    // prologue: stage tile 0 into buf0 (burst; drained at kt=0 boundary)
#pragma unroll
    for (int i = 0; i < 4; ++i) {
        async16(pa[i], smem + i * 8192 + wave * 1024);
        async16(pb[i], smem + 32768 + i * 8192 + wave * 1024);
        pa[i] += 64; pb[i] += 64;
    }

    const int rA0 = wm * 128 + col16;         // + p*32 + f*16
    const int rB0 = wn * 64 + col16;          // + n*16

#pragma unroll 2
    for (int kt = 0; kt < 64; ++kt) {
        char* sA  = smem + (kt & 1) * 65536;
        char* sB  = sA + 32768;
        char* sAn = smem + (((kt & 1) ^ 1)) * 65536;
        char* sBn = sAn + 32768;

        // Boundary: tile kt's 8 stage-loads were issued during kt-1 (a full
        // tile ~4000cyc ago; HBM lat ~900) -> drain is ~free. Barrier also
        // guarantees every wave's buffer-^1 ds_reads (from kt-1) retired
        // before any wave issues kt+1 stages into that buffer.
        asm volatile("s_waitcnt vmcnt(0)" ::: "memory");
        __builtin_amdgcn_s_barrier();

        // B fragments for the whole K-tile + A fragments for phase 0.
        // These 12 reads are the only lgkm-exposed latency per tile.
        bf16x8 bfr[4][2];
#pragma unroll
        for (int n = 0; n < 4; ++n)
#pragma unroll
            for (int ks = 0; ks < 2; ++ks) {
                const int r = rB0 + n * 16;
                const int ch = (ks * 4 + quad) ^ (r & 7);
                bfr[n][ks] = *(const bf16x8*)(sB + r * 128 + ch * 16);
            }
        bf16x8 af[2][2][2];                   // [pingpong][f][ks], static idx
#pragma unroll
        for (int f = 0; f < 2; ++f)
#pragma unroll
            for (int ks = 0; ks < 2; ++ks) {
                const int r = rA0 + f * 16;
                const int ch = (ks * 4 + quad) ^ (r & 7);
                af[0][f][ks] = *(const bf16x8*)(sA + r * 128 + ch * 16);
            }

        // 4 phases, software-pipelined by one: phase p issues A-reads for
        // p+1 (into af[nxt]) then runs MFMAs on af[cur] (read last phase,
        // already retired -> compiler emits lgkmcnt(4), no drain). The
        // ds_reads execute on the LDS pipe WHILE MFMAs run. No barriers.
#pragma unroll
        for (int p = 0; p < 4; ++p) {
            const int cur = p & 1, nxt = cur ^ 1;
            if (p < 3) {
#pragma unroll
                for (int f = 0; f < 2; ++f)
#pragma unroll
                    for (int ks = 0; ks < 2; ++ks) {
                        const int r = rA0 + (p + 1) * 32 + f * 16;
                        const int ch = (ks * 4 + quad) ^ (r & 7);
                        af[nxt][f][ks] = *(const bf16x8*)(sA + r * 128 + ch * 16);
                    }
            }
            if (kt < 63) {                    // stage 2 loads/phase for kt+1
                async16(pa[p], sAn + p * 8192 + wave * 1024);
                async16(pb[p], sBn + p * 8192 + wave * 1024);
                pa[p] += 64; pb[p] += 64;
            }
            __builtin_amdgcn_s_setprio(1);
#pragma unroll
            for (int f = 0; f < 2; ++f)
#pragma unroll
                for (int n = 0; n < 4; ++n) {
                    acc[p * 2 + f][n] = __builtin_amdgcn_mfma_f32_16x16x32_bf16(
                        af[cur][f][0], bfr[n][0], acc[p * 2 + f][n], 0, 0, 0);
                    acc[p * 2 + f][n] = __builtin_amdgcn_mfma_f32_16x16x32_bf16(
                        af[cur][f][1], bfr[n][1], acc[p * 2 + f][n], 0, 0, 0);
                }
            __builtin_amdgcn_s_setprio(0);
        }
    }

    // ---- epilogue: per-wave LDS round trip, C-layout -> (row, o) layout ----
    // Wave tile = 128 rows x 64 cols. 8 passes of (32 rows x 32 cols):
    // pass = seg (0..3, row segment) x h (0..1, col half). zs is WAVE-PRIVATE
    // (disjoint 8KB regions): one barrier total, then intra-wave ordering only.
    // FULLY UNROLLED (rule #20): every acc index must be compile-time or the
    // whole acc array is demoted to scratch (134MB/dispatch round trip).
    __syncthreads();                          // all K-loop LDS traffic done
    float* zs = (float*)(smem + wave * 8192); // 32 rows x 40 f32 = 5120B used
    const float* bp = biasp + ntile * 256 + wn * 64;
    const int o_idx = lane & 3;
    const int rgrp  = lane >> 2;              // 0..15

#pragma unroll
    for (int pass = 0; pass < 8; ++pass) {
        const int seg = pass >> 1;            // row segment: acc mf = seg*2 + {0,1}
        const int h   = pass & 1;             // col half:   acc nf = h*2 + {0,1}
#pragma unroll
        for (int mf2 = 0; mf2 < 2; ++mf2)
#pragma unroll
            for (int tl = 0; tl < 2; ++tl) {
                int nf = h * 2 + tl;
                int colz = tl * 16 + col16;
#pragma unroll
                for (int r = 0; r < 4; ++r)
                    zs[(mf2 * 16 + quad * 4 + r) * 40 + colz] = acc[seg * 2 + mf2][nf][r];
            }
        // intra-wave RAW through LDS: compiler inserts lgkmcnt wait

        float4 bb0 = *(const float4*)(bp + h * 32 + o_idx * 8);
        float4 bb1 = *(const float4*)(bp + h * 32 + o_idx * 8 + 4);
        int o_glob = ntile * 32 + wn * 8 + h * 4 + o_idx;

#pragma unroll
        for (int t = 0; t < 2; ++t) {
            int rowz = rgrp + t * 16;         // 0..31 within segment
            const float* zp = zs + rowz * 40 + o_idx * 8;
            float4 z0 = *(const float4*)zp;
            float4 z1 = *(const float4*)(zp + 4);
            int b = mtile * 256 + wm * 128 + seg * 32 + rowz;

            float fr = sigm(z0.x + bb0.x), fi = sigm(z0.y + bb0.y);
            float ir = sigm(z0.z + bb0.z), ii = sigm(z0.w + bb0.w);
            float ar = tanh_(z1.x + bb1.x), ai = tanh_(z1.y + bb1.y);
            float og_r = sigm(z1.z + bb1.z), og_i = sigm(z1.w + bb1.w);

            float cr = c_x[(size_t)b * 2048 + o_glob];
            float ci = c_x[(size_t)b * 2048 + 1024 + o_glob];

            float ct_r = (cr * fr - ci * fi) + (ar * ir - ai * ii);
            float ct_i = (cr * fi + ci * fr) + (ar * ii + ai * ir);
            float tr = tanh_(ct_r), ti = tanh_(ct_i);
            float ht_r = og_r * tr - og_i * ti;
            float ht_i = og_r * ti + og_i * tr;

            out[(size_t)b * 2048 + o_glob]               = ht_r;
            out[(size_t)b * 2048 + 1024 + o_glob]        = ht_i;
            out[HOFF + (size_t)b * 2048 + o_glob]        = ct_r;
            out[HOFF + (size_t)b * 2048 + 1024 + o_glob] = ct_i;
        }
        if (pass < 7)                          // drain zs reads before next pass
            asm volatile("s_waitcnt lgkmcnt(0)" ::: "memory");  // overwrites zs
    }
}

// ---------------------------------------------------------------------------
extern "C" void kernel_launch(void* const* d_in, const int* in_sizes, int n_in,
                              void* d_out, int out_size, void* d_ws, size_t ws_size,
                              hipStream_t stream) {
    const float* input = (const float*)d_in[0];
    const float* h_x   = (const float*)d_in[1];
    const float* c_x   = (const float*)d_in[2];
    const float* Uw_r  = (const float*)d_in[3];
    const float* Uw_i  = (const float*)d_in[4];
    const float* Ub_r  = (const float*)d_in[5];
    const float* Ub_i  = (const float*)d_in[6];
    const float* Ww_r  = (const float*)d_in[7];
    const float* Ww_i  = (const float*)d_in[8];
    const float* Wb_r  = (const float*)d_in[9];
    const float* Wb_i  = (const float*)d_in[10];
    float* out = (float*)d_out;

    // ws layout: X bf16 (32MB) | Wbig bf16 (64MB) | bias fp32 (32KB)  ~= 96MB
    unsigned short* Xb   = (unsigned short*)d_ws;
    unsigned short* Wb16 = Xb + (size_t)4096 * 4096;
    float* biasp = (float*)(Wb16 + (size_t)8192 * 4096);

    static bool s_attr = false;               // host-side, not a stream op:
    if (!s_attr) {                            // graph-capture safe
        hipFuncSetAttribute((const void*)clstm_gemm,
                            hipFuncAttributeMaxDynamicSharedMemorySize, 131072);
        s_attr = true;
    }

    pack_all<<<16384, 256, 0, stream>>>(input, h_x, Uw_r, Uw_i, Ww_r, Ww_i,
                                        Ub_r, Ub_i, Wb_r, Wb_i, Xb, Wb16, biasp);
    clstm_gemm<<<512, 512, 131072, stream>>>(Xb, Wb16, biasp, c_x, out);
}